// Round 2
// baseline (178.816 us; speedup 1.0000x reference)
//
#include <hip/hip_runtime.h>
#include <math.h>

// Problem constants
#define Bb   2
#define Hh   64
#define Ww   160
#define DIMc 256
#define Nn   (Hh * Ww)                 // 10240 positions per batch
#define SCALEf 0.17677669529663687f    // 32^-0.5

typedef unsigned short u16;
typedef unsigned int   u32;
typedef __bf16 bf16x8 __attribute__((ext_vector_type(8)));
typedef float  f32x4  __attribute__((ext_vector_type(4)));

// fp32 -> bf16 round-to-nearest-even
__device__ __forceinline__ u16 f2bf(float f) {
    u32 u = __float_as_uint(f);
    u += 0x7fffu + ((u >> 16) & 1u);
    return (u16)(u >> 16);
}
__device__ __forceinline__ u32 pack2(float lo, float hi) {
    return (u32)f2bf(lo) | ((u32)f2bf(hi) << 16);
}
// packed bf16 pair -> floats (exact)
__device__ __forceinline__ float bflo(u32 u) { return __uint_as_float(u << 16); }
__device__ __forceinline__ float bfhi(u32 u) { return __uint_as_float(u & 0xffff0000u); }

// async global(16B) -> LDS direct staging (wave-uniform base + lane*16)
__device__ __forceinline__ void gload16(const void* g, void* l) {
    __builtin_amdgcn_global_load_lds(
        (const __attribute__((address_space(1))) unsigned int*)g,
        (__attribute__((address_space(3))) unsigned int*)l,
        16, 0, 0);
}

// ---------------------------------------------------------------------------
// prep_w: weights only -> transposed bf16. Wt[wsel][n][k] = W[wsel][k][n].
// (x stays fp32; the QKV GEMM packs A in-register — bitwise-same RNE.)
// ---------------------------------------------------------------------------
__global__ __launch_bounds__(256) void prep_w(const float* __restrict__ Wq,
                                              const float* __restrict__ Wk,
                                              const float* __restrict__ Wv,
                                              const float* __restrict__ Wp,
                                              u16* __restrict__ WtAll)
{
    int id = blockIdx.x * 256 + threadIdx.x;     // 0 .. 262143
    int wsel = id >> 16;
    int rem  = id & 65535;
    int kk = rem >> 8, nn = rem & 255;
    const float* W = (wsel == 0) ? Wq : (wsel == 1) ? Wk : (wsel == 2) ? Wv : Wp;
    WtAll[(size_t)wsel * 65536 + nn * 256 + kk] = f2bf(W[kk * 256 + nn]);
}

// ---------------------------------------------------------------------------
// QKV GEMM: C = A[Mx256] @ Bt^T (Bt N-major). A fp32, packed to bf16 in-reg
// during staging (R0-proven); B bf16 staged via global_load_lds width=16.
// 256 threads = 4 waves in 2x2; wave = 4x4 grid of 16x16x32 MFMAs.
// Epilogue: C staged through the (reused) 32 KB LDS -> coalesced 16B stores.
// ---------------------------------------------------------------------------
__global__ __launch_bounds__(256) void gemm_qkv(const float* __restrict__ x,
                                                const u16* __restrict__ WtAll,
                                                u16* __restrict__ q,
                                                u16* __restrict__ k,
                                                u16* __restrict__ v)
{
    __shared__ __align__(16) char smem[32768];
    u16* sA = (u16*)smem;             //  8 KB: 128 rows x 32 k
    u16* sB = (u16*)(smem + 8192);    //  8 KB: 128 cols x 32 k

    const int z = blockIdx.z;
    u16* Cb = (z == 0) ? q : (z == 1) ? k : v;
    const u16* Btg = WtAll + (size_t)z * 65536;

    const int t    = threadIdx.x;
    const int lane = t & 63;
    const int wv   = t >> 6;
    const int wm   = wv & 1;      // wave m-half
    const int wn   = wv >> 1;     // wave n-half
    const int m0   = blockIdx.y * 128;
    const int n0   = blockIdx.x * 128;

    const int r0  = t >> 2;
    const int kc0 = (t & 3) * 8;          // elements (u16 / f32 alike)

    const int col  = lane & 15;
    const int quad = lane >> 4;

    f32x4 acc[4][4];
#pragma unroll
    for (int i = 0; i < 4; ++i)
#pragma unroll
        for (int j = 0; j < 4; ++j)
            acc[i][j] = (f32x4){0.f, 0.f, 0.f, 0.f};

    const u16* Bbase = Btg + (size_t)n0 * 256;
    // wave-uniform LDS bases for B staging (+ lane*16 applied by HW)
    char* ldsB0 = smem + 8192 + wv * 1024;
    char* ldsB1 = smem + 8192 + 4096 + wv * 1024;

    for (int k0 = 0; k0 < 256; k0 += 32) {
        // A: fp32 loads + in-register bf16 pack (issued before the barrier)
        const float* ap0 = x + (size_t)(m0 + r0) * 256 + k0 + kc0;
        const float* ap1 = x + (size_t)(m0 + 64 + r0) * 256 + k0 + kc0;
        float4 f0 = *(const float4*)ap0, f1 = *(const float4*)(ap0 + 4);
        float4 f2 = *(const float4*)ap1, f3 = *(const float4*)(ap1 + 4);
        uint4 a0, a1;
        a0.x = pack2(f0.x, f0.y); a0.y = pack2(f0.z, f0.w);
        a0.z = pack2(f1.x, f1.y); a0.w = pack2(f1.z, f1.w);
        a1.x = pack2(f2.x, f2.y); a1.y = pack2(f2.z, f2.w);
        a1.z = pack2(f3.x, f3.y); a1.w = pack2(f3.z, f3.w);

        __syncthreads();   // prior iteration's ds_reads complete before overwrite
        *(uint4*)(sA + r0 * 32 + kc0)        = a0;
        *(uint4*)(sA + (64 + r0) * 32 + kc0) = a1;
        gload16(Bbase + (size_t)r0        * 256 + k0 + kc0, ldsB0);
        gload16(Bbase + (size_t)(64 + r0) * 256 + k0 + kc0, ldsB1);
        __syncthreads();   // drains lgkmcnt (A ds_write) + vmcnt (B gload_lds)

        bf16x8 af[4], bfr[4];
#pragma unroll
        for (int mt = 0; mt < 4; ++mt)
            af[mt] = *(const bf16x8*)(sA + (wm * 64 + mt * 16 + col) * 32 + quad * 8);
#pragma unroll
        for (int nt = 0; nt < 4; ++nt)
            bfr[nt] = *(const bf16x8*)(sB + (wn * 64 + nt * 16 + col) * 32 + quad * 8);

#pragma unroll
        for (int mt = 0; mt < 4; ++mt)
#pragma unroll
            for (int nt = 0; nt < 4; ++nt)
                acc[mt][nt] = __builtin_amdgcn_mfma_f32_16x16x32_bf16(af[mt], bfr[nt], acc[mt][nt], 0, 0, 0);
    }

    // Epilogue: C/D layout col=lane&15 (n), row=quad*4+reg (m). Stage via LDS.
    __syncthreads();
    u16* sC = (u16*)smem;             // 128 x 128 bf16 = 32 KB
#pragma unroll
    for (int mt = 0; mt < 4; ++mt)
#pragma unroll
        for (int nt = 0; nt < 4; ++nt) {
            const int rw = wm * 64 + mt * 16 + quad * 4;
            const int cl = wn * 64 + nt * 16 + col;
#pragma unroll
            for (int rr = 0; rr < 4; ++rr)
                sC[(rw + rr) * 128 + cl] = f2bf(acc[mt][nt][rr]);
        }
    __syncthreads();
#pragma unroll
    for (int i = 0; i < 8; ++i) {
        int j   = i * 256 + t;
        int row = j >> 4;
        int off = (j & 15) * 8;
        *(uint4*)(Cb + (size_t)(m0 + row) * 256 + n0 + off) = *(const uint4*)(sC + row * 128 + off);
    }
}

// ---------------------------------------------------------------------------
// Fused attention + output projection.
// Block = 256 threads = 4 waves, 16 positions (4 per wave, sequential).
// Phase 1 (per wave, no sync): exact R1 attention math; ao row (256 bf16)
//   written to an 8 KB XOR-swizzled LDS tile instead of global memory.
//   Swizzle j ^= (m&7)<<4 — without it the proj A-frag read (stride 512 B)
//   is a 16-way bank conflict (G4).
// Phase 2 (after one barrier): proj = aoTile(16x256) @ Wp via MFMA.
//   Wave wv owns n in [wv*64, wv*64+64): 4 N-tiles x 8 K-steps.
//   Wp^T frags read directly from global (128 KB, L2-hot broadcast; per-quad
//   addresses are contiguous 64 B segments). K-order identical to the old
//   gemm_proj -> bitwise-identical output.
// ---------------------------------------------------------------------------
__global__ __launch_bounds__(256) void attn_proj(const u16* __restrict__ q,
                                                 const u16* __restrict__ k,
                                                 const u16* __restrict__ v,
                                                 const float* __restrict__ moff,
                                                 const u16* __restrict__ Wpt,
                                                 float* __restrict__ out)
{
    __shared__ __align__(16) u16 aoS[16 * 256];   // 8 KB, swizzled rows

    const int wv   = threadIdx.x >> 6;
    const int lane = threadIdx.x & 63;
    const int quad = lane >> 4;
    const int h    = lane & 7;
    const int a0   = lane >> 3;
    const int myh  = lane >> 3;

    // ---- Phase 1: attention, 4 positions per wave ----
    for (int i = 0; i < 4; ++i) {
        const int m   = wv * 4 + i;                 // row in the ao tile
        const int pos = blockIdx.x * 16 + m;
        const int rowbase = (pos >= Nn) ? Nn : 0;

        float2 mo = *(const float2*)(moff + (size_t)pos * 2);
        float ox = fminf(fmaxf(mo.x, 1.0f), (float)(Ww - 2) - 0.001f);
        float oy = fminf(fmaxf(mo.y, 1.0f), (float)(Hh - 2) - 0.001f);
        float mxf = floorf(ox), myf = floorf(oy);
        float fx = ox - mxf, fy = oy - myf;
        int imx = (int)mxf, imy = (int)myf;

        uint4 q4[4];
        {
            const uint4* qp = (const uint4*)(q + (size_t)pos * 256 + h * 32);
#pragma unroll
            for (int jj = 0; jj < 4; ++jj) q4[jj] = qp[jj];
        }

        float s[2];
#pragma unroll
        for (int p = 0; p < 2; ++p) {
            int a   = a0 + 8 * p;
            int row = rowbase + (imy + (a >> 2) - 1) * Ww + imx + (a & 3) - 1;
            const uint4* kp = (const uint4*)(k + (size_t)row * 256 + h * 32);
            float acc = 0.f;
#pragma unroll
            for (int jj = 0; jj < 4; ++jj) {
                uint4 kw = kp[jj];
                acc += bflo(q4[jj].x) * bflo(kw.x) + bfhi(q4[jj].x) * bfhi(kw.x)
                     + bflo(q4[jj].y) * bflo(kw.y) + bfhi(q4[jj].y) * bfhi(kw.y)
                     + bflo(q4[jj].z) * bflo(kw.z) + bfhi(q4[jj].z) * bfhi(kw.z)
                     + bflo(q4[jj].w) * bflo(kw.w) + bfhi(q4[jj].w) * bfhi(kw.w);
            }
            s[p] = acc * SCALEf;
        }

        auto wc = [](int r, float f) { return r == 0 ? 1.f - f : (r == 3 ? f : 1.f); };
        float bw0 = wc(a0 >> 2, fy) * wc(a0 & 3, fx);
        float bw1 = wc((a0 + 8) >> 2, fy) * wc(a0 & 3, fx);

        float mx = fmaxf(s[0], s[1]);
        mx = fmaxf(mx, __shfl_xor(mx, 8));
        mx = fmaxf(mx, __shfl_xor(mx, 16));
        mx = fmaxf(mx, __shfl_xor(mx, 32));
        float e0 = expf(s[0] - mx) * bw0;
        float e1 = expf(s[1] - mx) * bw1;
        float sum = e0 + e1;
        sum += __shfl_xor(sum, 8);
        sum += __shfl_xor(sum, 16);
        sum += __shfl_xor(sum, 32);
        float inv = 1.f / sum;
        float p0 = e0 * inv, p1 = e1 * inv;

        float acc0 = 0.f, acc1 = 0.f, acc2 = 0.f, acc3 = 0.f;
#pragma unroll
        for (int a = 0; a < 16; ++a) {
            int row = rowbase + (imy + (a >> 2) - 1) * Ww + imx + (a & 3) - 1;
            uint2 vw = *(const uint2*)(v + (size_t)row * 256 + 4 * lane);
            int src = ((a & 7) << 3) | myh;
            float pa = __shfl(a < 8 ? p0 : p1, src);
            acc0 += pa * bflo(vw.x); acc1 += pa * bfhi(vw.x);
            acc2 += pa * bflo(vw.y); acc3 += pa * bfhi(vw.y);
        }
        uint2 o;
        o.x = pack2(acc0, acc1);
        o.y = pack2(acc2, acc3);
        u32 off = (u32)m * 512 + (((u32)lane * 8) ^ (u32)((m & 7) << 4));
        *(uint2*)((char*)aoS + off) = o;
    }

    __syncthreads();

    // ---- Phase 2: proj MFMA. A-frag: row m = lane&15, k = k0 + quad*8. ----
    f32x4 pacc[4];
#pragma unroll
    for (int nt = 0; nt < 4; ++nt) pacc[nt] = (f32x4){0.f, 0.f, 0.f, 0.f};

    const int mrow = lane & 15;
#pragma unroll
    for (int k0 = 0; k0 < 256; k0 += 32) {
        u32 aoff = (u32)mrow * 512 + (((u32)((k0 + quad * 8) * 2)) ^ (u32)((mrow & 7) << 4));
        bf16x8 afr = *(const bf16x8*)((const char*)aoS + aoff);
#pragma unroll
        for (int nt = 0; nt < 4; ++nt) {
            const u16* bp = Wpt + (size_t)(wv * 64 + nt * 16 + mrow) * 256 + k0 + quad * 8;
            bf16x8 bfr = *(const bf16x8*)bp;
            pacc[nt] = __builtin_amdgcn_mfma_f32_16x16x32_bf16(afr, bfr, pacc[nt], 0, 0, 0);
        }
    }

    const int m0 = blockIdx.x * 16;
#pragma unroll
    for (int nt = 0; nt < 4; ++nt) {
        const int cl = wv * 64 + nt * 16 + mrow;
#pragma unroll
        for (int rr = 0; rr < 4; ++rr)
            out[(size_t)(m0 + quad * 4 + rr) * 256 + cl] = pacc[nt][rr];
    }
}

// ---------------------------------------------------------------------------
extern "C" void kernel_launch(void* const* d_in, const int* in_sizes, int n_in,
                              void* d_out, int out_size, void* d_ws, size_t ws_size,
                              hipStream_t stream)
{
    const float* x     = (const float*)d_in[0];
    const float* moff  = (const float*)d_in[1];
    const float* Wq    = (const float*)d_in[2];
    const float* Wk    = (const float*)d_in[3];
    const float* Wv    = (const float*)d_in[4];
    const float* Wproj = (const float*)d_in[5];
    float* out = (float*)d_out;

    const size_t NTOT = (size_t)Bb * Nn * DIMc;   // 5,242,880
    u16* ws    = (u16*)d_ws;
    u16* WtAll = ws;
    u16* q     = WtAll + 4 * 65536;
    u16* k     = q + NTOT;
    u16* v     = k + NTOT;

    prep_w<<<dim3(1024), dim3(256), 0, stream>>>(Wq, Wk, Wv, Wproj, WtAll);
    gemm_qkv<<<dim3(2, 160, 3), dim3(256), 0, stream>>>(x, WtAll, q, k, v);
    attn_proj<<<dim3(Bb * Nn / 16), dim3(256), 0, stream>>>(q, k, v, moff,
                                                            WtAll + (size_t)3 * 65536, out);
}

// Round 3
// 153.293 us; speedup vs baseline: 1.1665x; 1.1665x over previous
//
#include <hip/hip_runtime.h>
#include <math.h>

// Problem constants
#define Bb   2
#define Hh   64
#define Ww   160
#define DIMc 256
#define Nn   (Hh * Ww)                 // 10240 positions per batch
#define NPOS (Bb * Nn)                 // 20480 total positions
#define SCALEf 0.17677669529663687f    // 32^-0.5

typedef unsigned short u16;
typedef unsigned int   u32;
typedef __bf16 bf16x8 __attribute__((ext_vector_type(8)));
typedef float  f32x4  __attribute__((ext_vector_type(4)));

// fp32 -> bf16 round-to-nearest-even
__device__ __forceinline__ u16 f2bf(float f) {
    u32 u = __float_as_uint(f);
    u += 0x7fffu + ((u >> 16) & 1u);
    return (u16)(u >> 16);
}
__device__ __forceinline__ u32 pack2(float lo, float hi) {
    return (u32)f2bf(lo) | ((u32)f2bf(hi) << 16);
}
// packed bf16 pair -> floats (exact)
__device__ __forceinline__ float bflo(u32 u) { return __uint_as_float(u << 16); }
__device__ __forceinline__ float bfhi(u32 u) { return __uint_as_float(u & 0xffff0000u); }

// async global(16B) -> LDS direct staging (wave-uniform base + lane*16)
__device__ __forceinline__ void gload16(const void* g, void* l) {
    __builtin_amdgcn_global_load_lds(
        (const __attribute__((address_space(1))) unsigned int*)g,
        (__attribute__((address_space(3))) unsigned int*)l,
        16, 0, 0);
}

// window-center key for a position (must match attn's clamp math exactly)
__device__ __forceinline__ int win_key(const float* moff, int pos) {
    float2 mo = *(const float2*)(moff + (size_t)pos * 2);
    float ox = fminf(fmaxf(mo.x, 1.0f), (float)(Ww - 2) - 0.001f);
    float oy = fminf(fmaxf(mo.y, 1.0f), (float)(Hh - 2) - 0.001f);
    int imx = (int)floorf(ox), imy = (int)floorf(oy);
    return ((pos >= Nn) ? Nn : 0) + imy * Ww + imx;
}

// ---------------------------------------------------------------------------
// prep_w + hist zero: blocks [0,1024) transpose weights to bf16;
// blocks [1024,1104) zero the 20480-entry sort histogram.
// ---------------------------------------------------------------------------
__global__ __launch_bounds__(256) void prep_w(const float* __restrict__ Wq,
                                              const float* __restrict__ Wk,
                                              const float* __restrict__ Wv,
                                              const float* __restrict__ Wp,
                                              u16* __restrict__ WtAll,
                                              u32* __restrict__ hist)
{
    int id = blockIdx.x * 256 + threadIdx.x;     // 0 .. 282623
    if (id < 262144) {
        int wsel = id >> 16;
        int rem  = id & 65535;
        int kk = rem >> 8, nn = rem & 255;
        const float* W = (wsel == 0) ? Wq : (wsel == 1) ? Wk : (wsel == 2) ? Wv : Wp;
        WtAll[(size_t)wsel * 65536 + nn * 256 + kk] = f2bf(W[kk * 256 + nn]);
    } else {
        hist[id - 262144] = 0u;                  // 20480 entries
    }
}

// ---------------------------------------------------------------------------
// Counting sort of positions by window center (spatial locality for attn).
// ---------------------------------------------------------------------------
__global__ __launch_bounds__(256) void sort_count(const float* __restrict__ moff,
                                                  u32* __restrict__ keys,
                                                  u32* __restrict__ hist)
{
    int pos = blockIdx.x * 256 + threadIdx.x;    // 0 .. 20479
    int key = win_key(moff, pos);
    keys[pos] = (u32)key;
    atomicAdd(&hist[key], 1u);
}

__global__ __launch_bounds__(1024) void sort_scan(u32* __restrict__ hist)
{
    __shared__ u32 sc[1024];
    const int t = threadIdx.x;
    u32 loc[20];
    u32 s = 0;
#pragma unroll
    for (int j = 0; j < 20; ++j) { loc[j] = hist[t * 20 + j]; s += loc[j]; }
    sc[t] = s;
    __syncthreads();
    for (int off = 1; off < 1024; off <<= 1) {
        u32 vv = (t >= off) ? sc[t - off] : 0u;
        __syncthreads();
        sc[t] += vv;
        __syncthreads();
    }
    u32 ex = sc[t] - s;      // exclusive prefix
#pragma unroll
    for (int j = 0; j < 20; ++j) { hist[t * 20 + j] = ex; ex += loc[j]; }
}

__global__ __launch_bounds__(256) void sort_scatter(const u32* __restrict__ keys,
                                                    u32* __restrict__ hist,
                                                    u32* __restrict__ perm)
{
    int pos = blockIdx.x * 256 + threadIdx.x;
    u32 idx = atomicAdd(&hist[keys[pos]], 1u);
    perm[idx] = (u32)pos;
}

// ---------------------------------------------------------------------------
// QKV GEMM: C = A[Mx256] @ Bt^T (Bt N-major). A fp32, packed to bf16 in-reg
// during staging; B bf16 staged via global_load_lds width=16. (R2-proven)
// ---------------------------------------------------------------------------
__global__ __launch_bounds__(256) void gemm_qkv(const float* __restrict__ x,
                                                const u16* __restrict__ WtAll,
                                                u16* __restrict__ q,
                                                u16* __restrict__ k,
                                                u16* __restrict__ v)
{
    __shared__ __align__(16) char smem[32768];
    u16* sA = (u16*)smem;             //  8 KB: 128 rows x 32 k
    u16* sB = (u16*)(smem + 8192);    //  8 KB: 128 cols x 32 k

    const int z = blockIdx.z;
    u16* Cb = (z == 0) ? q : (z == 1) ? k : v;
    const u16* Btg = WtAll + (size_t)z * 65536;

    const int t    = threadIdx.x;
    const int lane = t & 63;
    const int wv   = t >> 6;
    const int wm   = wv & 1;
    const int wn   = wv >> 1;
    const int m0   = blockIdx.y * 128;
    const int n0   = blockIdx.x * 128;

    const int r0  = t >> 2;
    const int kc0 = (t & 3) * 8;

    const int col  = lane & 15;
    const int quad = lane >> 4;

    f32x4 acc[4][4];
#pragma unroll
    for (int i = 0; i < 4; ++i)
#pragma unroll
        for (int j = 0; j < 4; ++j)
            acc[i][j] = (f32x4){0.f, 0.f, 0.f, 0.f};

    const u16* Bbase = Btg + (size_t)n0 * 256;
    char* ldsB0 = smem + 8192 + wv * 1024;
    char* ldsB1 = smem + 8192 + 4096 + wv * 1024;

    for (int k0 = 0; k0 < 256; k0 += 32) {
        const float* ap0 = x + (size_t)(m0 + r0) * 256 + k0 + kc0;
        const float* ap1 = x + (size_t)(m0 + 64 + r0) * 256 + k0 + kc0;
        float4 f0 = *(const float4*)ap0, f1 = *(const float4*)(ap0 + 4);
        float4 f2 = *(const float4*)ap1, f3 = *(const float4*)(ap1 + 4);
        uint4 a0, a1;
        a0.x = pack2(f0.x, f0.y); a0.y = pack2(f0.z, f0.w);
        a0.z = pack2(f1.x, f1.y); a0.w = pack2(f1.z, f1.w);
        a1.x = pack2(f2.x, f2.y); a1.y = pack2(f2.z, f2.w);
        a1.z = pack2(f3.x, f3.y); a1.w = pack2(f3.z, f3.w);

        __syncthreads();
        *(uint4*)(sA + r0 * 32 + kc0)        = a0;
        *(uint4*)(sA + (64 + r0) * 32 + kc0) = a1;
        gload16(Bbase + (size_t)r0        * 256 + k0 + kc0, ldsB0);
        gload16(Bbase + (size_t)(64 + r0) * 256 + k0 + kc0, ldsB1);
        __syncthreads();

        bf16x8 af[4], bfr[4];
#pragma unroll
        for (int mt = 0; mt < 4; ++mt)
            af[mt] = *(const bf16x8*)(sA + (wm * 64 + mt * 16 + col) * 32 + quad * 8);
#pragma unroll
        for (int nt = 0; nt < 4; ++nt)
            bfr[nt] = *(const bf16x8*)(sB + (wn * 64 + nt * 16 + col) * 32 + quad * 8);

#pragma unroll
        for (int mt = 0; mt < 4; ++mt)
#pragma unroll
            for (int nt = 0; nt < 4; ++nt)
                acc[mt][nt] = __builtin_amdgcn_mfma_f32_16x16x32_bf16(af[mt], bfr[nt], acc[mt][nt], 0, 0, 0);
    }

    __syncthreads();
    u16* sC = (u16*)smem;             // 128 x 128 bf16 = 32 KB
#pragma unroll
    for (int mt = 0; mt < 4; ++mt)
#pragma unroll
        for (int nt = 0; nt < 4; ++nt) {
            const int rw = wm * 64 + mt * 16 + quad * 4;
            const int cl = wn * 64 + nt * 16 + col;
#pragma unroll
            for (int rr = 0; rr < 4; ++rr)
                sC[(rw + rr) * 128 + cl] = f2bf(acc[mt][nt][rr]);
        }
    __syncthreads();
#pragma unroll
    for (int i = 0; i < 8; ++i) {
        int j   = i * 256 + t;
        int row = j >> 4;
        int off = (j & 15) * 8;
        *(uint4*)(Cb + (size_t)(m0 + row) * 256 + n0 + off) = *(const uint4*)(sC + row * 128 + off);
    }
}

// ---------------------------------------------------------------------------
// Attention: ONE WAVE per position (R1-proven structure), but positions are
// consumed in window-sorted order via perm[], with a bijective XCD swizzle
// (5120 blocks = 8 x 640) so each XCD works one contiguous sorted band whose
// K/V footprint (~3 MB) fits its 4 MB L2.
// ---------------------------------------------------------------------------
__global__ __launch_bounds__(256) void attn_kernel(const u16* __restrict__ q,
                                                   const u16* __restrict__ k,
                                                   const u16* __restrict__ v,
                                                   const float* __restrict__ moff,
                                                   const u32* __restrict__ perm,
                                                   u16* __restrict__ ao)
{
    const int wv   = threadIdx.x >> 6;
    const int lane = threadIdx.x & 63;
    const int bid  = blockIdx.x;
    const int wg   = (bid & 7) * 640 + (bid >> 3);    // XCD-contiguous sorted chunks
    const int pos  = (int)perm[wg * 4 + wv];
    const int rowbase = (pos >= Nn) ? Nn : 0;

    float2 mo = *(const float2*)(moff + (size_t)pos * 2);
    float ox = fminf(fmaxf(mo.x, 1.0f), (float)(Ww - 2) - 0.001f);
    float oy = fminf(fmaxf(mo.y, 1.0f), (float)(Hh - 2) - 0.001f);
    float mxf = floorf(ox), myf = floorf(oy);
    float fx = ox - mxf, fy = oy - myf;
    int imx = (int)mxf, imy = (int)myf;

    const int h  = lane & 7;
    const int a0 = lane >> 3;

    uint4 q4[4];
    {
        const uint4* qp = (const uint4*)(q + (size_t)pos * 256 + h * 32);
#pragma unroll
        for (int jj = 0; jj < 4; ++jj) q4[jj] = qp[jj];
    }

    float s[2];
#pragma unroll
    for (int p = 0; p < 2; ++p) {
        int a   = a0 + 8 * p;
        int row = rowbase + (imy + (a >> 2) - 1) * Ww + imx + (a & 3) - 1;
        const uint4* kp = (const uint4*)(k + (size_t)row * 256 + h * 32);
        float acc = 0.f;
#pragma unroll
        for (int jj = 0; jj < 4; ++jj) {
            uint4 kw = kp[jj];
            acc += bflo(q4[jj].x) * bflo(kw.x) + bfhi(q4[jj].x) * bfhi(kw.x)
                 + bflo(q4[jj].y) * bflo(kw.y) + bfhi(q4[jj].y) * bfhi(kw.y)
                 + bflo(q4[jj].z) * bflo(kw.z) + bfhi(q4[jj].z) * bfhi(kw.z)
                 + bflo(q4[jj].w) * bflo(kw.w) + bfhi(q4[jj].w) * bfhi(kw.w);
        }
        s[p] = acc * SCALEf;
    }

    auto wc = [](int r, float f) { return r == 0 ? 1.f - f : (r == 3 ? f : 1.f); };
    float bw0 = wc(a0 >> 2, fy) * wc(a0 & 3, fx);
    float bw1 = wc((a0 + 8) >> 2, fy) * wc(a0 & 3, fx);

    float m = fmaxf(s[0], s[1]);
    m = fmaxf(m, __shfl_xor(m, 8));
    m = fmaxf(m, __shfl_xor(m, 16));
    m = fmaxf(m, __shfl_xor(m, 32));
    float e0 = expf(s[0] - m) * bw0;
    float e1 = expf(s[1] - m) * bw1;
    float sum = e0 + e1;
    sum += __shfl_xor(sum, 8);
    sum += __shfl_xor(sum, 16);
    sum += __shfl_xor(sum, 32);
    float inv = 1.f / sum;
    float p0 = e0 * inv, p1 = e1 * inv;

    float acc0 = 0.f, acc1 = 0.f, acc2 = 0.f, acc3 = 0.f;
    const int myh = lane >> 3;
#pragma unroll
    for (int a = 0; a < 16; ++a) {
        int row = rowbase + (imy + (a >> 2) - 1) * Ww + imx + (a & 3) - 1;
        uint2 vw = *(const uint2*)(v + (size_t)row * 256 + 4 * lane);
        int src = ((a & 7) << 3) | myh;
        float pa = __shfl(a < 8 ? p0 : p1, src);
        acc0 += pa * bflo(vw.x); acc1 += pa * bfhi(vw.x);
        acc2 += pa * bflo(vw.y); acc3 += pa * bfhi(vw.y);
    }
    uint2 o;
    o.x = pack2(acc0, acc1);
    o.y = pack2(acc2, acc3);
    *(uint2*)(ao + (size_t)pos * 256 + 4 * lane) = o;
}

// ---------------------------------------------------------------------------
// Output projection: out = ao(bf16) @ Wp, fp32 out. Both operands staged via
// global_load_lds width=16 (R1-proven core, BF16OUT=false path).
// ---------------------------------------------------------------------------
__global__ __launch_bounds__(256) void gemm_proj(const u16* __restrict__ Ab,
                                                 const u16* __restrict__ Btg,
                                                 float* __restrict__ Cf)
{
    __shared__ __align__(16) char smem[32768];
    u16* sA = (u16*)smem;
    u16* sB = (u16*)(smem + 8192);

    const int t    = threadIdx.x;
    const int lane = t & 63;
    const int wv   = t >> 6;
    const int wm   = wv & 1;
    const int wn   = wv >> 1;
    const int m0   = blockIdx.y * 128;
    const int n0   = blockIdx.x * 128;

    const int r0  = t >> 2;
    const int kc0 = (t & 3) * 8;

    const int col  = lane & 15;
    const int quad = lane >> 4;

    f32x4 acc[4][4];
#pragma unroll
    for (int i = 0; i < 4; ++i)
#pragma unroll
        for (int j = 0; j < 4; ++j)
            acc[i][j] = (f32x4){0.f, 0.f, 0.f, 0.f};

    const u16* Bbase = Btg + (size_t)n0 * 256;
    char* ldsA0 = smem + wv * 1024;
    char* ldsA1 = smem + 4096 + wv * 1024;
    char* ldsB0 = smem + 8192 + wv * 1024;
    char* ldsB1 = smem + 8192 + 4096 + wv * 1024;

    for (int k0 = 0; k0 < 256; k0 += 32) {
        __syncthreads();
        gload16(Ab    + (size_t)(m0 + r0)      * 256 + k0 + kc0, ldsA0);
        gload16(Ab    + (size_t)(m0 + 64 + r0) * 256 + k0 + kc0, ldsA1);
        gload16(Bbase + (size_t)r0             * 256 + k0 + kc0, ldsB0);
        gload16(Bbase + (size_t)(64 + r0)      * 256 + k0 + kc0, ldsB1);
        __syncthreads();

        bf16x8 af[4], bfr[4];
#pragma unroll
        for (int mt = 0; mt < 4; ++mt)
            af[mt] = *(const bf16x8*)(sA + (wm * 64 + mt * 16 + col) * 32 + quad * 8);
#pragma unroll
        for (int nt = 0; nt < 4; ++nt)
            bfr[nt] = *(const bf16x8*)(sB + (wn * 64 + nt * 16 + col) * 32 + quad * 8);

#pragma unroll
        for (int mt = 0; mt < 4; ++mt)
#pragma unroll
            for (int nt = 0; nt < 4; ++nt)
                acc[mt][nt] = __builtin_amdgcn_mfma_f32_16x16x32_bf16(af[mt], bfr[nt], acc[mt][nt], 0, 0, 0);
    }

    __syncthreads();
    float* sC = (float*)smem;         // 64 x 128 fp32 = 32 KB per pass
#pragma unroll
    for (int ph = 0; ph < 2; ++ph) {
        if (wm == ph) {
#pragma unroll
            for (int mt = 0; mt < 4; ++mt)
#pragma unroll
                for (int nt = 0; nt < 4; ++nt) {
                    const int rw = mt * 16 + quad * 4;
                    const int cl = wn * 64 + nt * 16 + col;
#pragma unroll
                    for (int rr = 0; rr < 4; ++rr)
                        sC[(rw + rr) * 128 + cl] = acc[mt][nt][rr];
                }
        }
        __syncthreads();
#pragma unroll
        for (int i = 0; i < 8; ++i) {
            int j   = i * 256 + t;
            int row = j >> 5;
            int off = (j & 31) * 4;
            *(float4*)(Cf + (size_t)(m0 + ph * 64 + row) * 256 + n0 + off) =
                *(const float4*)(sC + row * 128 + off);
        }
        __syncthreads();
    }
}

// ---------------------------------------------------------------------------
extern "C" void kernel_launch(void* const* d_in, const int* in_sizes, int n_in,
                              void* d_out, int out_size, void* d_ws, size_t ws_size,
                              hipStream_t stream)
{
    const float* x     = (const float*)d_in[0];
    const float* moff  = (const float*)d_in[1];
    const float* Wq    = (const float*)d_in[2];
    const float* Wk    = (const float*)d_in[3];
    const float* Wv    = (const float*)d_in[4];
    const float* Wproj = (const float*)d_in[5];
    float* out = (float*)d_out;

    const size_t NTOT = (size_t)Bb * Nn * DIMc;   // 5,242,880
    u16* ws    = (u16*)d_ws;
    u16* WtAll = ws;
    u16* q     = WtAll + 4 * 65536;
    u16* k     = q + NTOT;
    u16* v     = k + NTOT;
    u16* ao    = v + NTOT;
    u32* keys  = (u32*)(ao + NTOT);
    u32* hist  = keys + NPOS;
    u32* perm  = hist + NPOS;

    prep_w<<<dim3(1104), dim3(256), 0, stream>>>(Wq, Wk, Wv, Wproj, WtAll, hist);
    sort_count<<<dim3(80), dim3(256), 0, stream>>>(moff, keys, hist);
    sort_scan<<<dim3(1), dim3(1024), 0, stream>>>(hist);
    sort_scatter<<<dim3(80), dim3(256), 0, stream>>>(keys, hist, perm);
    gemm_qkv<<<dim3(2, 160, 3), dim3(256), 0, stream>>>(x, WtAll, q, k, v);
    attn_kernel<<<dim3(NPOS / 4), dim3(256), 0, stream>>>(q, k, v, moff, perm, ao);
    gemm_proj<<<dim3(2, 160, 1), dim3(256), 0, stream>>>(ao, WtAll + (size_t)3 * 65536, out);
}

// Round 4
// 149.343 us; speedup vs baseline: 1.1974x; 1.0264x over previous
//
#include <hip/hip_runtime.h>
#include <math.h>

// Problem constants
#define Bb   2
#define Hh   64
#define Ww   160
#define DIMc 256
#define Nn   (Hh * Ww)                 // 10240 positions per batch
#define NPOS (Bb * Nn)                 // 20480 total positions
#define SCALEf 0.17677669529663687f    // 32^-0.5

typedef unsigned short u16;
typedef unsigned int   u32;
typedef __bf16 bf16x8 __attribute__((ext_vector_type(8)));
typedef float  f32x4  __attribute__((ext_vector_type(4)));

// fp32 -> bf16 round-to-nearest-even
__device__ __forceinline__ u16 f2bf(float f) {
    u32 u = __float_as_uint(f);
    u += 0x7fffu + ((u >> 16) & 1u);
    return (u16)(u >> 16);
}
__device__ __forceinline__ u32 pack2(float lo, float hi) {
    return (u32)f2bf(lo) | ((u32)f2bf(hi) << 16);
}
// packed bf16 pair -> floats (exact)
__device__ __forceinline__ float bflo(u32 u) { return __uint_as_float(u << 16); }
__device__ __forceinline__ float bfhi(u32 u) { return __uint_as_float(u & 0xffff0000u); }

// async global(16B) -> LDS direct staging (wave-uniform base + lane*16)
__device__ __forceinline__ void gload16(const void* g, void* l) {
    __builtin_amdgcn_global_load_lds(
        (const __attribute__((address_space(1))) unsigned int*)g,
        (__attribute__((address_space(3))) unsigned int*)l,
        16, 0, 0);
}

// ---------------------------------------------------------------------------
// prep_w: weights -> transposed bf16. Wt[wsel][n][k] = W[wsel][k][n].
// ---------------------------------------------------------------------------
__global__ __launch_bounds__(256) void prep_w(const float* __restrict__ Wq,
                                              const float* __restrict__ Wk,
                                              const float* __restrict__ Wv,
                                              const float* __restrict__ Wp,
                                              u16* __restrict__ WtAll)
{
    int id = blockIdx.x * 256 + threadIdx.x;     // 0 .. 262143
    int wsel = id >> 16;
    int rem  = id & 65535;
    int kk = rem >> 8, nn = rem & 255;
    const float* W = (wsel == 0) ? Wq : (wsel == 1) ? Wk : (wsel == 2) ? Wv : Wp;
    WtAll[(size_t)wsel * 65536 + nn * 256 + kk] = f2bf(W[kk * 256 + nn]);
}

// ---------------------------------------------------------------------------
// QKV GEMM: C = A[Mx256] @ Bt^T (Bt N-major). A fp32, packed to bf16 in-reg
// during staging; B bf16 staged via global_load_lds width=16.
// For z in {0,1} (q,k) the output columns are PERMUTED to the attn-friendly
// interleave n' = (dim>>3)*64 + head*8 + (dim&7)  (layout [row][jj][h][8d]),
// so the attention K/Q reads are granule-contiguous (8 lanes x 16B = 128 B
// per window row instead of 16B pieces at 64 B stride). Pure index permute:
// bitwise-identical values. v (z==2) stays in natural order.
// ---------------------------------------------------------------------------
__global__ __launch_bounds__(256) void gemm_qkv(const float* __restrict__ x,
                                                const u16* __restrict__ WtAll,
                                                u16* __restrict__ q,
                                                u16* __restrict__ k,
                                                u16* __restrict__ v)
{
    __shared__ __align__(16) char smem[32768];
    u16* sA = (u16*)smem;             //  8 KB: 128 rows x 32 k
    u16* sB = (u16*)(smem + 8192);    //  8 KB: 128 cols x 32 k

    const int z = blockIdx.z;
    u16* Cb = (z == 0) ? q : (z == 1) ? k : v;
    const u16* Btg = WtAll + (size_t)z * 65536;

    const int t    = threadIdx.x;
    const int lane = t & 63;
    const int wv   = t >> 6;
    const int wm   = wv & 1;
    const int wn   = wv >> 1;
    const int m0   = blockIdx.y * 128;
    const int n0   = blockIdx.x * 128;

    const int r0  = t >> 2;
    const int kc0 = (t & 3) * 8;

    const int col  = lane & 15;
    const int quad = lane >> 4;

    f32x4 acc[4][4];
#pragma unroll
    for (int i = 0; i < 4; ++i)
#pragma unroll
        for (int j = 0; j < 4; ++j)
            acc[i][j] = (f32x4){0.f, 0.f, 0.f, 0.f};

    const u16* Bbase = Btg + (size_t)n0 * 256;
    char* ldsB0 = smem + 8192 + wv * 1024;
    char* ldsB1 = smem + 8192 + 4096 + wv * 1024;

    for (int k0 = 0; k0 < 256; k0 += 32) {
        const float* ap0 = x + (size_t)(m0 + r0) * 256 + k0 + kc0;
        const float* ap1 = x + (size_t)(m0 + 64 + r0) * 256 + k0 + kc0;
        float4 f0 = *(const float4*)ap0, f1 = *(const float4*)(ap0 + 4);
        float4 f2 = *(const float4*)ap1, f3 = *(const float4*)(ap1 + 4);
        uint4 a0, a1;
        a0.x = pack2(f0.x, f0.y); a0.y = pack2(f0.z, f0.w);
        a0.z = pack2(f1.x, f1.y); a0.w = pack2(f1.z, f1.w);
        a1.x = pack2(f2.x, f2.y); a1.y = pack2(f2.z, f2.w);
        a1.z = pack2(f3.x, f3.y); a1.w = pack2(f3.z, f3.w);

        __syncthreads();
        *(uint4*)(sA + r0 * 32 + kc0)        = a0;
        *(uint4*)(sA + (64 + r0) * 32 + kc0) = a1;
        gload16(Bbase + (size_t)r0        * 256 + k0 + kc0, ldsB0);
        gload16(Bbase + (size_t)(64 + r0) * 256 + k0 + kc0, ldsB1);
        __syncthreads();

        bf16x8 af[4], bfr[4];
#pragma unroll
        for (int mt = 0; mt < 4; ++mt)
            af[mt] = *(const bf16x8*)(sA + (wm * 64 + mt * 16 + col) * 32 + quad * 8);
#pragma unroll
        for (int nt = 0; nt < 4; ++nt)
            bfr[nt] = *(const bf16x8*)(sB + (wn * 64 + nt * 16 + col) * 32 + quad * 8);

#pragma unroll
        for (int mt = 0; mt < 4; ++mt)
#pragma unroll
            for (int nt = 0; nt < 4; ++nt)
                acc[mt][nt] = __builtin_amdgcn_mfma_f32_16x16x32_bf16(af[mt], bfr[nt], acc[mt][nt], 0, 0, 0);
    }

    __syncthreads();
    u16* sC = (u16*)smem;             // 128 x 128 bf16 = 32 KB
#pragma unroll
    for (int mt = 0; mt < 4; ++mt)
#pragma unroll
        for (int nt = 0; nt < 4; ++nt) {
            const int rw = wm * 64 + mt * 16 + quad * 4;
            const int cl = wn * 64 + nt * 16 + col;
#pragma unroll
            for (int rr = 0; rr < 4; ++rr)
                sC[(rw + rr) * 128 + cl] = f2bf(acc[mt][nt][rr]);
        }
    __syncthreads();
#pragma unroll
    for (int i = 0; i < 8; ++i) {
        int j   = i * 256 + t;
        int row = j >> 4;
        int off = (j & 15) * 8;
        // global 16B-chunk index and (for q,k) the interleaved destination
        int cg  = (n0 >> 3) + (j & 15);                    // 0..31
        int dst = (z == 2) ? cg * 8 : ((cg & 3) * 64 + (cg >> 2) * 8);
        *(uint4*)(Cb + (size_t)(m0 + row) * 256 + dst) = *(const uint4*)(sC + row * 128 + off);
    }
}

// ---------------------------------------------------------------------------
// Attention: ONE WAVE per position (R1-proven). q/k are in the interleaved
// layout [row][jj][head][8dims]; per (jj) K-load the wave's 64 lanes cover
// 8 window rows x 128 B contiguous -> full 64 B granule utilization.
// V phase unchanged (already contiguous). Math order identical -> bitwise
// same result as the natural-layout kernel.
// ---------------------------------------------------------------------------
__global__ __launch_bounds__(256) void attn_kernel(const u16* __restrict__ q,
                                                   const u16* __restrict__ k,
                                                   const u16* __restrict__ v,
                                                   const float* __restrict__ moff,
                                                   u16* __restrict__ ao)
{
    const int wv   = threadIdx.x >> 6;
    const int lane = threadIdx.x & 63;
    const int pos  = blockIdx.x * 4 + wv;
    const int rowbase = (pos >= Nn) ? Nn : 0;

    float2 mo = *(const float2*)(moff + (size_t)pos * 2);
    float ox = fminf(fmaxf(mo.x, 1.0f), (float)(Ww - 2) - 0.001f);
    float oy = fminf(fmaxf(mo.y, 1.0f), (float)(Hh - 2) - 0.001f);
    float mxf = floorf(ox), myf = floorf(oy);
    float fx = ox - mxf, fy = oy - myf;
    int imx = (int)mxf, imy = (int)myf;

    const int h  = lane & 7;
    const int a0 = lane >> 3;

    // interleaved: element (head h, dim jj*8+d) at offset jj*64 + h*8 + d
    uint4 q4[4];
    {
        const u16* qp = q + (size_t)pos * 256 + h * 8;
#pragma unroll
        for (int jj = 0; jj < 4; ++jj) q4[jj] = *(const uint4*)(qp + jj * 64);
    }

    float s[2];
#pragma unroll
    for (int p = 0; p < 2; ++p) {
        int a   = a0 + 8 * p;
        int row = rowbase + (imy + (a >> 2) - 1) * Ww + imx + (a & 3) - 1;
        const u16* kp = k + (size_t)row * 256 + h * 8;
        float acc = 0.f;
#pragma unroll
        for (int jj = 0; jj < 4; ++jj) {
            uint4 kw = *(const uint4*)(kp + jj * 64);
            acc += bflo(q4[jj].x) * bflo(kw.x) + bfhi(q4[jj].x) * bfhi(kw.x)
                 + bflo(q4[jj].y) * bflo(kw.y) + bfhi(q4[jj].y) * bfhi(kw.y)
                 + bflo(q4[jj].z) * bflo(kw.z) + bfhi(q4[jj].z) * bfhi(kw.z)
                 + bflo(q4[jj].w) * bflo(kw.w) + bfhi(q4[jj].w) * bfhi(kw.w);
        }
        s[p] = acc * SCALEf;
    }

    auto wc = [](int r, float f) { return r == 0 ? 1.f - f : (r == 3 ? f : 1.f); };
    float bw0 = wc(a0 >> 2, fy) * wc(a0 & 3, fx);
    float bw1 = wc((a0 + 8) >> 2, fy) * wc(a0 & 3, fx);

    float m = fmaxf(s[0], s[1]);
    m = fmaxf(m, __shfl_xor(m, 8));
    m = fmaxf(m, __shfl_xor(m, 16));
    m = fmaxf(m, __shfl_xor(m, 32));
    float e0 = expf(s[0] - m) * bw0;
    float e1 = expf(s[1] - m) * bw1;
    float sum = e0 + e1;
    sum += __shfl_xor(sum, 8);
    sum += __shfl_xor(sum, 16);
    sum += __shfl_xor(sum, 32);
    float inv = 1.f / sum;
    float p0 = e0 * inv, p1 = e1 * inv;

    float acc0 = 0.f, acc1 = 0.f, acc2 = 0.f, acc3 = 0.f;
    const int myh = lane >> 3;
#pragma unroll
    for (int a = 0; a < 16; ++a) {
        int row = rowbase + (imy + (a >> 2) - 1) * Ww + imx + (a & 3) - 1;
        uint2 vw = *(const uint2*)(v + (size_t)row * 256 + 4 * lane);
        int src = ((a & 7) << 3) | myh;
        float pa = __shfl(a < 8 ? p0 : p1, src);
        acc0 += pa * bflo(vw.x); acc1 += pa * bfhi(vw.x);
        acc2 += pa * bflo(vw.y); acc3 += pa * bfhi(vw.y);
    }
    uint2 o;
    o.x = pack2(acc0, acc1);
    o.y = pack2(acc2, acc3);
    *(uint2*)(ao + (size_t)pos * 256 + 4 * lane) = o;
}

// ---------------------------------------------------------------------------
// Output projection: out = ao(bf16) @ Wp, fp32 out; both operands staged via
// global_load_lds width=16.
// ---------------------------------------------------------------------------
__global__ __launch_bounds__(256) void gemm_proj(const u16* __restrict__ Ab,
                                                 const u16* __restrict__ Btg,
                                                 float* __restrict__ Cf)
{
    __shared__ __align__(16) char smem[32768];
    u16* sA = (u16*)smem;
    u16* sB = (u16*)(smem + 8192);

    const int t    = threadIdx.x;
    const int lane = t & 63;
    const int wv   = t >> 6;
    const int wm   = wv & 1;
    const int wn   = wv >> 1;
    const int m0   = blockIdx.y * 128;
    const int n0   = blockIdx.x * 128;

    const int r0  = t >> 2;
    const int kc0 = (t & 3) * 8;

    const int col  = lane & 15;
    const int quad = lane >> 4;

    f32x4 acc[4][4];
#pragma unroll
    for (int i = 0; i < 4; ++i)
#pragma unroll
        for (int j = 0; j < 4; ++j)
            acc[i][j] = (f32x4){0.f, 0.f, 0.f, 0.f};

    const u16* Bbase = Btg + (size_t)n0 * 256;
    char* ldsA0 = smem + wv * 1024;
    char* ldsA1 = smem + 4096 + wv * 1024;
    char* ldsB0 = smem + 8192 + wv * 1024;
    char* ldsB1 = smem + 8192 + 4096 + wv * 1024;

    for (int k0 = 0; k0 < 256; k0 += 32) {
        __syncthreads();
        gload16(Ab    + (size_t)(m0 + r0)      * 256 + k0 + kc0, ldsA0);
        gload16(Ab    + (size_t)(m0 + 64 + r0) * 256 + k0 + kc0, ldsA1);
        gload16(Bbase + (size_t)r0             * 256 + k0 + kc0, ldsB0);
        gload16(Bbase + (size_t)(64 + r0)      * 256 + k0 + kc0, ldsB1);
        __syncthreads();

        bf16x8 af[4], bfr[4];
#pragma unroll
        for (int mt = 0; mt < 4; ++mt)
            af[mt] = *(const bf16x8*)(sA + (wm * 64 + mt * 16 + col) * 32 + quad * 8);
#pragma unroll
        for (int nt = 0; nt < 4; ++nt)
            bfr[nt] = *(const bf16x8*)(sB + (wn * 64 + nt * 16 + col) * 32 + quad * 8);

#pragma unroll
        for (int mt = 0; mt < 4; ++mt)
#pragma unroll
            for (int nt = 0; nt < 4; ++nt)
                acc[mt][nt] = __builtin_amdgcn_mfma_f32_16x16x32_bf16(af[mt], bfr[nt], acc[mt][nt], 0, 0, 0);
    }

    __syncthreads();
    float* sC = (float*)smem;         // 64 x 128 fp32 = 32 KB per pass
#pragma unroll
    for (int ph = 0; ph < 2; ++ph) {
        if (wm == ph) {
#pragma unroll
            for (int mt = 0; mt < 4; ++mt)
#pragma unroll
                for (int nt = 0; nt < 4; ++nt) {
                    const int rw = mt * 16 + quad * 4;
                    const int cl = wn * 64 + nt * 16 + col;
#pragma unroll
                    for (int rr = 0; rr < 4; ++rr)
                        sC[(rw + rr) * 128 + cl] = acc[mt][nt][rr];
                }
        }
        __syncthreads();
#pragma unroll
        for (int i = 0; i < 8; ++i) {
            int j   = i * 256 + t;
            int row = j >> 5;
            int off = (j & 31) * 4;
            *(float4*)(Cf + (size_t)(m0 + ph * 64 + row) * 256 + n0 + off) =
                *(const float4*)(sC + row * 128 + off);
        }
        __syncthreads();
    }
}

// ---------------------------------------------------------------------------
extern "C" void kernel_launch(void* const* d_in, const int* in_sizes, int n_in,
                              void* d_out, int out_size, void* d_ws, size_t ws_size,
                              hipStream_t stream)
{
    const float* x     = (const float*)d_in[0];
    const float* moff  = (const float*)d_in[1];
    const float* Wq    = (const float*)d_in[2];
    const float* Wk    = (const float*)d_in[3];
    const float* Wv    = (const float*)d_in[4];
    const float* Wproj = (const float*)d_in[5];
    float* out = (float*)d_out;

    const size_t NTOT = (size_t)Bb * Nn * DIMc;   // 5,242,880
    u16* ws    = (u16*)d_ws;
    u16* WtAll = ws;
    u16* q     = WtAll + 4 * 65536;
    u16* k     = q + NTOT;
    u16* v     = k + NTOT;
    u16* ao    = v + NTOT;

    prep_w<<<dim3(1024), dim3(256), 0, stream>>>(Wq, Wk, Wv, Wproj, WtAll);
    gemm_qkv<<<dim3(2, 160, 3), dim3(256), 0, stream>>>(x, WtAll, q, k, v);
    attn_kernel<<<dim3(NPOS / 4), dim3(256), 0, stream>>>(q, k, v, moff, ao);
    gemm_proj<<<dim3(2, 160, 1), dim3(256), 0, stream>>>(ao, WtAll + (size_t)3 * 65536, out);
}